// Round 12
// baseline (160.680 us; speedup 1.0000x reference)
//
#include <hip/hip_runtime.h>
#include <math.h>

#define N1 4096
#define N2 1024
#define C1 128
#define C2 256
#define CIN 384
#define H 256
#define BATCH 16
#define BN_EPS 1e-5f

typedef __attribute__((ext_vector_type(8))) short bf16x8;
typedef __attribute__((ext_vector_type(4))) float f32x4;

__device__ inline float bf2f(short s) {
    union { unsigned u; float f; } x;
    x.u = ((unsigned)(unsigned short)s) << 16;
    return x.f;
}
__device__ inline short f2bf(float f) {
    union { float f; unsigned u; } x; x.f = f;
    unsigned r = x.u + 0x7fffu + ((x.u >> 16) & 1u);
    return (short)(r >> 16);
}

typedef const __attribute__((address_space(1))) unsigned int guint;
typedef __attribute__((address_space(3))) unsigned int luint;
__device__ inline void gll16(const void* g, void* l) {
    __builtin_amdgcn_global_load_lds((guint*)g, (luint*)l, 16, 0, 0);
}

// ---------------- KNN: 3-fma distance (monotone), guarded exact top-3 ----------------
__global__ __launch_bounds__(256)
void knn_kernel(const float* __restrict__ c1, const float* __restrict__ c2,
                float4* __restrict__ pk) {
    __shared__ __align__(16) float4 sc[N2];     // (-2x, -2y, -2z, |c2|^2)
    __shared__ float md[64 * 13];
    __shared__ int   mi[64 * 13];
    const int b = blockIdx.y;
    const float* c2b = c2 + (size_t)b * 3 * N2;
    for (int j = threadIdx.x; j < N2; j += 256) {
        float xx = c2b[j], yy = c2b[N2 + j], zz = c2b[2 * N2 + j];
        sc[j] = make_float4(-2.f * xx, -2.f * yy, -2.f * zz, xx * xx + yy * yy + zz * zz);
    }
    __syncthreads();

    const int t = threadIdx.x;
    const int q = t & 63;
    const int quarter = t >> 6;
    const int n = blockIdx.x * 64 + q;
    const float* c1b = c1 + (size_t)b * 3 * N1;
    const float x = c1b[n], y = c1b[N1 + n], z = c1b[2 * N1 + n];

    // d' = |c2|^2 - 2<c1,c2>  (= true dist^2 - s1; monotone per query)
    float d0 = 3.4e38f, d1 = 3.4e38f, d2 = 3.4e38f;
    int i0 = 0, i1 = 0, i2 = 0;
    const int j0 = quarter * 256;
    #pragma unroll 4
    for (int jj = 0; jj < 256; ++jj) {
        const int j = j0 + jj;
        float4 cc = sc[j];
        float d = fmaf(x, cc.x, fmaf(y, cc.y, fmaf(z, cc.z, cc.w)));
        bool c2v = d < d2;
        if (__any(c2v)) {      // skipping when d>=d2 is exact (med3/min are no-ops)
            bool c0v = d < d0, c1v = d < d1;
            i2 = c1v ? i1 : (c2v ? j : i2);
            i1 = c0v ? i0 : (c1v ? j : i1);
            i0 = c0v ? j  : i0;
            d2 = __builtin_amdgcn_fmed3f(d1, d2, d);
            d1 = __builtin_amdgcn_fmed3f(d0, d1, d);
            d0 = fminf(d0, d);
        }
    }
    const int mb = q * 13 + quarter * 3;
    md[mb + 0] = d0; md[mb + 1] = d1; md[mb + 2] = d2;
    mi[mb + 0] = i0; mi[mb + 1] = i1; mi[mb + 2] = i2;
    __syncthreads();

    if (t < 64) {
        float e0 = 3.4e38f, e1 = 3.4e38f, e2 = 3.4e38f;
        int a0 = 0, a1 = 0, a2 = 0;
        #pragma unroll
        for (int r = 0; r < 12; ++r) {
            const int rr = t * 13 + (r / 3) * 3 + (r % 3);
            float d = md[rr]; int j = mi[rr];
            bool c0 = d < e0, c1v = d < e1, c2v = d < e2;
            e2 = c1v ? e1 : (c2v ? d : e2);  a2 = c1v ? a1 : (c2v ? j : a2);
            e1 = c0 ? e0 : (c1v ? d : e1);   a1 = c0 ? a0 : (c1v ? j : a1);
            e0 = c0 ? d  : e0;               a0 = c0 ? j  : a0;
        }
        const float s1 = x * x + y * y + z * z;   // restore true dist^2
        float r0 = 1.0f / (e0 + s1 + 1e-8f);
        float r1 = 1.0f / (e1 + s1 + 1e-8f);
        float r2 = 1.0f / (e2 + s1 + 1e-8f);
        float rs = r0 + r1 + r2;
        unsigned pack = (unsigned)a0 | ((unsigned)a1 << 10) | ((unsigned)a2 << 20);
        pk[(size_t)b * N1 + n] = make_float4(__uint_as_float(pack), r0 / rs, r1 / rs, r2 / rs);
    }
}

// ---------------- Prep: W [256][K] f32 -> swizzled bf16 [K/8][256][8] ----------------
__global__ __launch_bounds__(256)
void prep_w(const float* __restrict__ W, short* __restrict__ Wsw, int K) {
    const int nkb = K >> 3;
    const int id = blockIdx.x * 256 + threadIdx.x;
    if (id >= 256 * nkb) return;
    const int m = id / nkb, kb = id % nkb;
    const float* src = W + (size_t)m * K + kb * 8;
    bf16x8 v;
    #pragma unroll
    for (int j = 0; j < 8; ++j) v[j] = f2bf(src[j]);
    *(bf16x8*)(Wsw + ((size_t)kb * 256 + m) * 8) = v;
}

// ---------------- Transpose f2 [b][c][j] f32 -> f2t [b][j][c] bf16 ----------------
__global__ __launch_bounds__(256)
void transpose_f2(const float* __restrict__ f2, short* __restrict__ f2t) {
    __shared__ float st[32][33];
    const int j0 = blockIdx.x * 32, c0 = blockIdx.y * 32, b = blockIdx.z;
    const int t = threadIdx.x;
    {
        const int cc = t >> 3, jj = (t & 7) * 4;
        const float* src = f2 + ((size_t)b * C2 + c0 + cc) * N2 + j0 + jj;
        float4 v = *(const float4*)src;
        st[cc][jj + 0] = v.x; st[cc][jj + 1] = v.y;
        st[cc][jj + 2] = v.z; st[cc][jj + 3] = v.w;
    }
    __syncthreads();
    {
        const int j = t >> 3, cb = (t & 7) * 4;
        short4 v = { f2bf(st[cb + 0][j]), f2bf(st[cb + 1][j]),
                     f2bf(st[cb + 2][j]), f2bf(st[cb + 3][j]) };
        *(short4*)(f2t + ((size_t)b * N2 + j0 + j) * C2 + c0 + cb) = v;
    }
}

// ---------------- prep_B1: interp rows in kc layout [b][kb 0..31][n][8] ----------------
__global__ __launch_bounds__(256)
void prep_B1(const short* __restrict__ f2t, const float4* __restrict__ pk,
             short* __restrict__ B1) {
    const int b = blockIdx.y;
    const int n = blockIdx.x * 256 + threadIdx.x;
    float4 v = pk[(size_t)b * N1 + n];
    unsigned u = __float_as_uint(v.x);
    const short* r0 = f2t + ((size_t)b * N2 + (u & 1023u)) * C2;
    const short* r1 = f2t + ((size_t)b * N2 + ((u >> 10) & 1023u)) * C2;
    const short* r2 = f2t + ((size_t)b * N2 + ((u >> 20) & 1023u)) * C2;
    short* ob = B1 + ((size_t)b * 32 * N1 + n) * 8;
    #pragma unroll 4
    for (int kb = 0; kb < 32; ++kb) {
        bf16x8 g0 = *(const bf16x8*)(r0 + kb * 8);
        bf16x8 g1 = *(const bf16x8*)(r1 + kb * 8);
        bf16x8 g2 = *(const bf16x8*)(r2 + kb * 8);
        bf16x8 o;
        #pragma unroll
        for (int e = 0; e < 8; ++e)
            o[e] = f2bf(fmaf(v.w, bf2f(g2[e]), fmaf(v.z, bf2f(g1[e]), v.y * bf2f(g0[e]))));
        *(bf16x8*)(ob + (size_t)kb * N1 * 8) = o;
    }
}

// ---------------- B-resident MFMA GEMM: one-shot LDS B-tile, barrier-free K-loop --------
// BM=256 (full M), BN=64, 256 threads / 4 waves, wave = 64(M)x64(N).
// Whole B-tile staged to LDS at start via gll16 (32/48 KB -> 100-140 KB in flight per CU),
// ONE __syncthreads, then K-loop reads A from L2-hot Wsw direct to registers. B read once.
// NT=12 (gemm1): B kb 0..15 from f1 (f32, reg->LDS), kb 16..47 gll16 from B1.
// NT=8, BN=true (gemm2): all 32 kb gll16 from y1kc; BN1+ReLU applied on fragment read.
template<int NT, bool BN>
__global__ __launch_bounds__(256)
void gemm_kernel(const short* __restrict__ Wsw,
                 const float* __restrict__ f1, const short* __restrict__ Bkc,
                 const float* __restrict__ scale, const float* __restrict__ shift,
                 short* __restrict__ Ykc, float2* __restrict__ P) {
    constexpr bool M0 = (NT == 12);

    __shared__ __align__(16) short B_lds[4 * NT][64][8];  // 48 KB / 32 KB
    __shared__ float sc_s[256], sh_s[256];

    const int t = threadIdx.x;
    const int blk = blockIdx.x;
    const int b = blk >> 6, nt = blk & 63;
    const int n0 = nt * 64;

    const int lane = t & 63, wv = t >> 6;
    const int wm = wv;                       // wave owns M rows wm*64..+63
    const int l16 = lane & 15, lq = lane >> 4;

    if (BN) { sc_s[t] = scale[t]; sh_s[t] = shift[t]; }

    const short* Bb = Bkc + (size_t)b * 32 * N1 * 8;

    // ---- one-shot B staging: 32 gll16 units (8 per wave) ----
    #pragma unroll
    for (int i = 0; i < 8; ++i) {
        const int u = wv * 8 + i;                       // 0..31
        const int dst_kb = M0 ? (16 + u) : u;
        const short* g = Bb + ((size_t)u * N1 + n0 + lane) * 8;
        gll16(g, &B_lds[dst_kb][0][0]);
    }
    if (M0) {
        // f1 (f32) -> B_lds kb 0..15: thread t owns kb=t>>4, n-quad=(t&15)*4
        const float* f1b = f1 + (size_t)b * C1 * N1;
        const int kbt = t >> 4, nq = (t & 15) * 4;
        float4 fv[8];
        #pragma unroll
        for (int e = 0; e < 8; ++e)
            fv[e] = *(const float4*)(f1b + (size_t)(kbt * 8 + e) * N1 + n0 + nq);
        #pragma unroll
        for (int j = 0; j < 4; ++j) {
            bf16x8 pv;
            pv[0] = f2bf(j == 0 ? fv[0].x : j == 1 ? fv[0].y : j == 2 ? fv[0].z : fv[0].w);
            pv[1] = f2bf(j == 0 ? fv[1].x : j == 1 ? fv[1].y : j == 2 ? fv[1].z : fv[1].w);
            pv[2] = f2bf(j == 0 ? fv[2].x : j == 1 ? fv[2].y : j == 2 ? fv[2].z : fv[2].w);
            pv[3] = f2bf(j == 0 ? fv[3].x : j == 1 ? fv[3].y : j == 2 ? fv[3].z : fv[3].w);
            pv[4] = f2bf(j == 0 ? fv[4].x : j == 1 ? fv[4].y : j == 2 ? fv[4].z : fv[4].w);
            pv[5] = f2bf(j == 0 ? fv[5].x : j == 1 ? fv[5].y : j == 2 ? fv[5].z : fv[5].w);
            pv[6] = f2bf(j == 0 ? fv[6].x : j == 1 ? fv[6].y : j == 2 ? fv[6].z : fv[6].w);
            pv[7] = f2bf(j == 0 ? fv[7].x : j == 1 ? fv[7].y : j == 2 ? fv[7].z : fv[7].w);
            *(bf16x8*)&B_lds[kbt][nq + j][0] = pv;
        }
    }
    __syncthreads();   // single barrier: drains gll16 (vmcnt) + ds_writes

    f32x4 acc[4][4];
    #pragma unroll
    for (int i = 0; i < 4; ++i)
        #pragma unroll
        for (int j = 0; j < 4; ++j)
            acc[i][j] = (f32x4){0.f, 0.f, 0.f, 0.f};

    // ---- barrier-free K-loop: A direct from global (L2-hot), B from LDS ----
    #pragma unroll
    for (int s = 0; s < NT; ++s) {
        bf16x8 a[4], bb4[4];
        const short* ap = Wsw + ((size_t)(s * 4 + lq) * 256 + wm * 64 + l16) * 8;
        #pragma unroll
        for (int f = 0; f < 4; ++f)
            a[f] = *(const bf16x8*)(ap + (size_t)f * 16 * 8);
        if (BN) {
            const int k0 = s * 32 + lq * 8;
            float sck[8], shk[8];
            #pragma unroll
            for (int e = 0; e < 8; ++e) { sck[e] = sc_s[k0 + e]; shk[e] = sh_s[k0 + e]; }
            #pragma unroll
            for (int f = 0; f < 4; ++f) {
                bf16x8 raw = *(const bf16x8*)&B_lds[s * 4 + lq][f * 16 + l16][0];
                #pragma unroll
                for (int e = 0; e < 8; ++e)
                    bb4[f][e] = f2bf(fmaxf(fmaf(bf2f(raw[e]), sck[e], shk[e]), 0.f));
            }
        } else {
            #pragma unroll
            for (int f = 0; f < 4; ++f)
                bb4[f] = *(const bf16x8*)&B_lds[s * 4 + lq][f * 16 + l16][0];
        }
        #pragma unroll
        for (int i = 0; i < 4; ++i)
            #pragma unroll
            for (int j = 0; j < 4; ++j)
                acc[i][j] = __builtin_amdgcn_mfma_f32_16x16x32_bf16(a[i], bb4[j], acc[i][j], 0, 0, 0);
    }

    // ---- epilogue: k-chunked store [kb][n][8] ----
    short* Yb = Ykc + (size_t)b * 32 * N1 * 8;
    #pragma unroll
    for (int i = 0; i < 4; ++i) {
        const int kb = wm * 8 + i * 2 + (lq >> 1);
        const int kr0 = (lq & 1) * 4;
        #pragma unroll
        for (int j = 0; j < 4; ++j) {
            const int n = n0 + j * 16 + l16;
            short4 v = { f2bf(acc[i][j][0]), f2bf(acc[i][j][1]),
                         f2bf(acc[i][j][2]), f2bf(acc[i][j][3]) };
            *(short4*)(Yb + ((size_t)kb * N1 + n) * 8 + kr0) = v;
        }
    }

    // ---- BN partials: each wave owns its 64 channels exclusively -> direct store ----
    #pragma unroll
    for (int i = 0; i < 4; ++i) {
        #pragma unroll
        for (int r = 0; r < 4; ++r) {
            float s = 0.f, qq = 0.f;
            #pragma unroll
            for (int j = 0; j < 4; ++j) {
                float xv = acc[i][j][r];
                s += xv; qq += xv * xv;
            }
            #pragma unroll
            for (int msk = 1; msk < 16; msk <<= 1) {
                s  += __shfl_xor(s, msk);
                qq += __shfl_xor(qq, msk);
            }
            if (l16 == 0) {
                const int c = wm * 64 + i * 16 + lq * 4 + r;
                P[(size_t)c * 1024 + blk] = make_float2(s, qq);
            }
        }
    }
}

// ---------------- BN reduce: partials [256][1024] -> scale/shift ----------------
__global__ __launch_bounds__(256)
void bn_reduce(const float2* __restrict__ P, const float* __restrict__ g,
               const float* __restrict__ be, float* __restrict__ scale,
               float* __restrict__ shift) {
    const int c = blockIdx.x, t = threadIdx.x;
    float s = 0.f, q = 0.f;
    #pragma unroll
    for (int r = 0; r < 4; ++r) {
        float2 v = P[(size_t)c * 1024 + r * 256 + t];
        s += v.x; q += v.y;
    }
    __shared__ float ss[256], sq[256];
    ss[t] = s; sq[t] = q;
    __syncthreads();
    for (int o = 128; o > 0; o >>= 1) {
        if (t < o) { ss[t] += ss[t + o]; sq[t] += sq[t + o]; }
        __syncthreads();
    }
    if (t == 0) {
        const float inv = 1.0f / (float)(BATCH * N1);
        float mean = ss[0] * inv;
        float var  = sq[0] * inv - mean * mean;
        float sc = g[c] / sqrtf(var + BN_EPS);
        scale[c] = sc;
        shift[c] = be[c] - mean * sc;
    }
}

// ---------------- Final BN2+ReLU: y2kc -> f32 out (normal layout) ----------------
__global__ __launch_bounds__(256)
void final_bn_relu(const short* __restrict__ y2kc, const float* __restrict__ scale,
                   const float* __restrict__ shift, float* __restrict__ out) {
    const int t = threadIdx.x;
    const int n0 = blockIdx.x * 1024 + t * 4;
    const int kb = blockIdx.y, b = blockIdx.z;
    const short* src = y2kc + ((size_t)(b * 32 + kb) * N1 + n0) * 8;
    bf16x8 v0 = *(const bf16x8*)(src);
    bf16x8 v1 = *(const bf16x8*)(src + 8);
    bf16x8 v2 = *(const bf16x8*)(src + 16);
    bf16x8 v3 = *(const bf16x8*)(src + 24);
    #pragma unroll
    for (int e = 0; e < 8; ++e) {
        const float sc = scale[kb * 8 + e], sh = shift[kb * 8 + e];
        float4 o;
        o.x = fmaxf(fmaf(bf2f(v0[e]), sc, sh), 0.f);
        o.y = fmaxf(fmaf(bf2f(v1[e]), sc, sh), 0.f);
        o.z = fmaxf(fmaf(bf2f(v2[e]), sc, sh), 0.f);
        o.w = fmaxf(fmaf(bf2f(v3[e]), sc, sh), 0.f);
        *(float4*)(out + ((size_t)(b * 256 + kb * 8 + e) * N1) + n0) = o;
    }
}

extern "C" void kernel_launch(void* const* d_in, const int* in_sizes, int n_in,
                              void* d_out, int out_size, void* d_ws, size_t ws_size,
                              hipStream_t stream) {
    const float* c1  = (const float*)d_in[0];
    const float* c2  = (const float*)d_in[1];
    const float* f1  = (const float*)d_in[2];
    const float* f2  = (const float*)d_in[3];
    const float* W1  = (const float*)d_in[4];
    const float* g1  = (const float*)d_in[6];
    const float* be1 = (const float*)d_in[7];
    const float* W2  = (const float*)d_in[8];
    const float* g2  = (const float*)d_in[10];
    const float* be2 = (const float*)d_in[11];
    float* out = (float*)d_out;

    // ws regions (sequential-kernel overlap, peak ~67.6 MiB):
    // [0,32 MiB):  B1 (prep_B1 -> gemm1), then y2kc (gemm2 -> final)
    // [32,64):     f2t (8 MiB, transpose -> prep_B1), then y1kc (gemm1 -> gemm2)
    // [64..):      W1s | W2s | pk | P(2 MiB) | scales
    char* ws = (char*)d_ws;
    short*  B1   = (short*)ws;
    short*  y2kc = (short*)ws;
    short*  f2t  = (short*)(ws + (32u << 20));
    short*  y1kc = (short*)(ws + (32u << 20));
    short*  W1s  = (short*)(ws + (64u << 20));
    short*  W2s  = (short*)(ws + (64u << 20) + (256u << 10));
    float4* pk   = (float4*)(ws + (64u << 20) + (512u << 10));
    float2* P    = (float2*)(ws + (64u << 20) + (1536u << 10));
    float* scale1 = (float*)(ws + (64u << 20) + (3584u << 10));
    float* shift1 = scale1 + 256;
    float* scale2 = shift1 + 256;
    float* shift2 = scale2 + 256;

    prep_w<<<48, 256, 0, stream>>>(W1, W1s, CIN);
    prep_w<<<32, 256, 0, stream>>>(W2, W2s, H);
    transpose_f2<<<dim3(N2 / 32, C2 / 32, BATCH), 256, 0, stream>>>(f2, f2t);
    knn_kernel<<<dim3(N1 / 64, BATCH), 256, 0, stream>>>(c1, c2, pk);
    prep_B1<<<dim3(N1 / 256, BATCH), 256, 0, stream>>>(f2t, pk, B1);

    gemm_kernel<12, false><<<1024, 256, 0, stream>>>(
        W1s, f1, B1, nullptr, nullptr, y1kc, P);
    bn_reduce<<<256, 256, 0, stream>>>(P, g1, be1, scale1, shift1);

    gemm_kernel<8, true><<<1024, 256, 0, stream>>>(
        W2s, nullptr, y1kc, scale1, shift1, y2kc, P);
    bn_reduce<<<256, 256, 0, stream>>>(P, g2, be2, scale2, shift2);

    final_bn_relu<<<dim3(N1 / 1024, 32, BATCH), 256, 0, stream>>>(y2kc, scale2, shift2, out);
}

// Round 13
// 140.180 us; speedup vs baseline: 1.1462x; 1.1462x over previous
//
#include <hip/hip_runtime.h>
#include <math.h>

#define N1 4096
#define N2 1024
#define C1 128
#define C2 256
#define CIN 384
#define H 256
#define BATCH 16
#define BN_EPS 1e-5f

typedef __attribute__((ext_vector_type(8))) short bf16x8;
typedef __attribute__((ext_vector_type(4))) float f32x4;

__device__ inline float bf2f(short s) {
    union { unsigned u; float f; } x;
    x.u = ((unsigned)(unsigned short)s) << 16;
    return x.f;
}
__device__ inline short f2bf(float f) {
    union { float f; unsigned u; } x; x.f = f;
    unsigned r = x.u + 0x7fffu + ((x.u >> 16) & 1u);
    return (short)(r >> 16);
}

typedef const __attribute__((address_space(1))) unsigned int guint;
typedef __attribute__((address_space(3))) unsigned int luint;
__device__ inline void gll16(const void* g, void* l) {
    __builtin_amdgcn_global_load_lds((guint*)g, (luint*)l, 16, 0, 0);
}

// ---------------- KNN v4: 512 thr, 8-way split, branchless exact top-3 ----------------
__global__ __launch_bounds__(512)
void knn_kernel(const float* __restrict__ c1, const float* __restrict__ c2,
                float4* __restrict__ pk) {
    __shared__ __align__(16) float4 sc[N2];     // (-2x, -2y, -2z, |c2|^2) 16KB
    __shared__ float md[64 * 25];
    __shared__ int   mi[64 * 25];
    const int b = blockIdx.y;
    const float* c2b = c2 + (size_t)b * 3 * N2;
    for (int j = threadIdx.x; j < N2; j += 512) {
        float xx = c2b[j], yy = c2b[N2 + j], zz = c2b[2 * N2 + j];
        sc[j] = make_float4(-2.f * xx, -2.f * yy, -2.f * zz, xx * xx + yy * yy + zz * zz);
    }
    __syncthreads();

    const int t = threadIdx.x;
    const int q = t & 63;
    const int oct = t >> 6;                 // 0..7
    const int n = blockIdx.x * 64 + q;
    const float* c1b = c1 + (size_t)b * 3 * N1;
    const float x = c1b[n], y = c1b[N1 + n], z = c1b[2 * N1 + n];

    // d' = |c2|^2 - 2<c1,c2>  (monotone shift of true dist^2 by -|c1|^2)
    float d0 = 3.4e38f, d1 = 3.4e38f, d2 = 3.4e38f;
    int i0 = 0, i1 = 0, i2 = 0;
    const int j0 = oct * 128;
    #pragma unroll 8
    for (int jj = 0; jj < 128; ++jj) {
        const int j = j0 + jj;
        float4 cc = sc[j];
        float d = fmaf(x, cc.x, fmaf(y, cc.y, fmaf(z, cc.z, cc.w)));
        bool c0v = d < d0, c1v = d < d1, c2v = d < d2;
        i2 = c1v ? i1 : (c2v ? j : i2);
        i1 = c0v ? i0 : (c1v ? j : i1);
        i0 = c0v ? j  : i0;
        d2 = __builtin_amdgcn_fmed3f(d1, d2, d);
        d1 = __builtin_amdgcn_fmed3f(d0, d1, d);
        d0 = fminf(d0, d);
    }
    const int mb = q * 25 + oct * 3;
    md[mb + 0] = d0; md[mb + 1] = d1; md[mb + 2] = d2;
    mi[mb + 0] = i0; mi[mb + 1] = i1; mi[mb + 2] = i2;
    __syncthreads();

    if (t < 64) {
        // merge 8 octs' top-3 (oct order = j-ascending -> strict-< keeps top_k ties)
        float e0 = 3.4e38f, e1 = 3.4e38f, e2 = 3.4e38f;
        int a0 = 0, a1 = 0, a2 = 0;
        #pragma unroll
        for (int r = 0; r < 24; ++r) {
            const int rr = t * 25 + r;
            float d = md[rr]; int j = mi[rr];
            bool c0 = d < e0, c1v = d < e1, c2v = d < e2;
            e2 = c1v ? e1 : (c2v ? d : e2);  a2 = c1v ? a1 : (c2v ? j : a2);
            e1 = c0 ? e0 : (c1v ? d : e1);   a1 = c0 ? a0 : (c1v ? j : a1);
            e0 = c0 ? d  : e0;               a0 = c0 ? j  : a0;
        }
        const float s1 = x * x + y * y + z * z;   // restore true dist^2
        float r0 = 1.0f / (e0 + s1 + 1e-8f);
        float r1 = 1.0f / (e1 + s1 + 1e-8f);
        float r2 = 1.0f / (e2 + s1 + 1e-8f);
        float rs = r0 + r1 + r2;
        unsigned pack = (unsigned)a0 | ((unsigned)a1 << 10) | ((unsigned)a2 << 20);
        pk[(size_t)b * N1 + n] = make_float4(__uint_as_float(pack), r0 / rs, r1 / rs, r2 / rs);
    }
}

// ---------------- Prep: W [256][K] f32 -> swizzled bf16 [K/8][256][8] ----------------
__global__ __launch_bounds__(256)
void prep_w(const float* __restrict__ W, short* __restrict__ Wsw, int K) {
    const int nkb = K >> 3;
    const int id = blockIdx.x * 256 + threadIdx.x;
    if (id >= 256 * nkb) return;
    const int m = id / nkb, kb = id % nkb;
    const float* src = W + (size_t)m * K + kb * 8;
    bf16x8 v;
    #pragma unroll
    for (int j = 0; j < 8; ++j) v[j] = f2bf(src[j]);
    *(bf16x8*)(Wsw + ((size_t)kb * 256 + m) * 8) = v;
}

// ---------------- Transpose f2 [b][c][j] f32 -> f2t [b][j][c] bf16 ----------------
__global__ __launch_bounds__(256)
void transpose_f2(const float* __restrict__ f2, short* __restrict__ f2t) {
    __shared__ float st[32][33];
    const int j0 = blockIdx.x * 32, c0 = blockIdx.y * 32, b = blockIdx.z;
    const int t = threadIdx.x;
    {
        const int cc = t >> 3, jj = (t & 7) * 4;
        const float* src = f2 + ((size_t)b * C2 + c0 + cc) * N2 + j0 + jj;
        float4 v = *(const float4*)src;
        st[cc][jj + 0] = v.x; st[cc][jj + 1] = v.y;
        st[cc][jj + 2] = v.z; st[cc][jj + 3] = v.w;
    }
    __syncthreads();
    {
        const int j = t >> 3, cb = (t & 7) * 4;
        short4 v = { f2bf(st[cb + 0][j]), f2bf(st[cb + 1][j]),
                     f2bf(st[cb + 2][j]), f2bf(st[cb + 3][j]) };
        *(short4*)(f2t + ((size_t)b * N2 + j0 + j) * C2 + c0 + cb) = v;
    }
}

// ---------------- B-resident MFMA GEMM: one-shot LDS B-tile, barrier-free K-loop --------
// BM=256 (full M), BN=64, 256 threads / 4 waves, wave = 64(M)x64(N). B read once.
// NT=12 (gemm1): B kb 0..15 from f1 (f32 reg-stage); kb 16..47 INTERP gathered from
//                f2t (L2/L3-resident) using per-column pk — prep_B1 fused here.
// NT=8, BN=true (gemm2): all 32 kb gll16 from y1kc; BN1+ReLU applied on fragment read.
template<int NT, bool BN>
__global__ __launch_bounds__(256)
void gemm_kernel(const short* __restrict__ Wsw,
                 const float* __restrict__ f1, const short* __restrict__ Bkc,
                 const short* __restrict__ f2t, const float4* __restrict__ pk,
                 const float* __restrict__ scale, const float* __restrict__ shift,
                 short* __restrict__ Ykc, float2* __restrict__ P) {
    constexpr bool M0 = (NT == 12);

    __shared__ __align__(16) short B_lds[4 * NT][64][8];  // 48 KB / 32 KB
    __shared__ float sc_s[256], sh_s[256];

    const int t = threadIdx.x;
    const int blk = blockIdx.x;
    const int b = blk >> 6, nt = blk & 63;
    const int n0 = nt * 64;

    const int lane = t & 63, wv = t >> 6;
    const int wm = wv;
    const int l16 = lane & 15, lq = lane >> 4;

    if (BN) { sc_s[t] = scale[t]; sh_s[t] = shift[t]; }

    if (M0) {
        // ---- fused interp staging: thread owns column t&63, kb-chunks 4i+(t>>6) ----
        const int col = t & 63;
        const int kq  = t >> 6;
        float4 pv = pk[(size_t)b * N1 + n0 + col];
        unsigned u = __float_as_uint(pv.x);
        const short* rr0 = f2t + ((size_t)b * N2 + (u & 1023u)) * C2;
        const short* rr1 = f2t + ((size_t)b * N2 + ((u >> 10) & 1023u)) * C2;
        const short* rr2 = f2t + ((size_t)b * N2 + ((u >> 20) & 1023u)) * C2;
        #pragma unroll
        for (int i = 0; i < 8; ++i) {
            const int kbl = i * 4 + kq;                 // 0..31
            bf16x8 g0 = *(const bf16x8*)(rr0 + kbl * 8);
            bf16x8 g1 = *(const bf16x8*)(rr1 + kbl * 8);
            bf16x8 g2 = *(const bf16x8*)(rr2 + kbl * 8);
            bf16x8 o;
            #pragma unroll
            for (int e = 0; e < 8; ++e)
                o[e] = f2bf(fmaf(pv.w, bf2f(g2[e]), fmaf(pv.z, bf2f(g1[e]), pv.y * bf2f(g0[e]))));
            *(bf16x8*)&B_lds[16 + kbl][col][0] = o;
        }
        // ---- f1 (f32) -> B_lds kb 0..15: thread owns kb=t>>4, n-quad=(t&15)*4 ----
        const float* f1b = f1 + (size_t)b * C1 * N1;
        const int kbt = t >> 4, nq = (t & 15) * 4;
        float4 fv[8];
        #pragma unroll
        for (int e = 0; e < 8; ++e)
            fv[e] = *(const float4*)(f1b + (size_t)(kbt * 8 + e) * N1 + n0 + nq);
        #pragma unroll
        for (int j = 0; j < 4; ++j) {
            bf16x8 pw;
            pw[0] = f2bf(j == 0 ? fv[0].x : j == 1 ? fv[0].y : j == 2 ? fv[0].z : fv[0].w);
            pw[1] = f2bf(j == 0 ? fv[1].x : j == 1 ? fv[1].y : j == 2 ? fv[1].z : fv[1].w);
            pw[2] = f2bf(j == 0 ? fv[2].x : j == 1 ? fv[2].y : j == 2 ? fv[2].z : fv[2].w);
            pw[3] = f2bf(j == 0 ? fv[3].x : j == 1 ? fv[3].y : j == 2 ? fv[3].z : fv[3].w);
            pw[4] = f2bf(j == 0 ? fv[4].x : j == 1 ? fv[4].y : j == 2 ? fv[4].z : fv[4].w);
            pw[5] = f2bf(j == 0 ? fv[5].x : j == 1 ? fv[5].y : j == 2 ? fv[5].z : fv[5].w);
            pw[6] = f2bf(j == 0 ? fv[6].x : j == 1 ? fv[6].y : j == 2 ? fv[6].z : fv[6].w);
            pw[7] = f2bf(j == 0 ? fv[7].x : j == 1 ? fv[7].y : j == 2 ? fv[7].z : fv[7].w);
            *(bf16x8*)&B_lds[kbt][nq + j][0] = pw;
        }
    } else {
        // ---- one-shot gll16 staging from kc-layout y1kc ----
        const short* Bb = Bkc + (size_t)b * 32 * N1 * 8;
        #pragma unroll
        for (int i = 0; i < 8; ++i) {
            const int u = wv * 8 + i;                   // 0..31
            const short* g = Bb + ((size_t)u * N1 + n0 + lane) * 8;
            gll16(g, &B_lds[u][0][0]);
        }
    }
    __syncthreads();   // drains vmcnt (gll16) + ds_writes

    f32x4 acc[4][4];
    #pragma unroll
    for (int i = 0; i < 4; ++i)
        #pragma unroll
        for (int j = 0; j < 4; ++j)
            acc[i][j] = (f32x4){0.f, 0.f, 0.f, 0.f};

    // ---- barrier-free K-loop: A direct from global (L2-hot), B from LDS ----
    #pragma unroll
    for (int s = 0; s < NT; ++s) {
        bf16x8 a[4], bb4[4];
        const short* ap = Wsw + ((size_t)(s * 4 + lq) * 256 + wm * 64 + l16) * 8;
        #pragma unroll
        for (int f = 0; f < 4; ++f)
            a[f] = *(const bf16x8*)(ap + (size_t)f * 16 * 8);
        if (BN) {
            const int k0 = s * 32 + lq * 8;
            float sck[8], shk[8];
            #pragma unroll
            for (int e = 0; e < 8; ++e) { sck[e] = sc_s[k0 + e]; shk[e] = sh_s[k0 + e]; }
            #pragma unroll
            for (int f = 0; f < 4; ++f) {
                bf16x8 raw = *(const bf16x8*)&B_lds[s * 4 + lq][f * 16 + l16][0];
                #pragma unroll
                for (int e = 0; e < 8; ++e)
                    bb4[f][e] = f2bf(fmaxf(fmaf(bf2f(raw[e]), sck[e], shk[e]), 0.f));
            }
        } else {
            #pragma unroll
            for (int f = 0; f < 4; ++f)
                bb4[f] = *(const bf16x8*)&B_lds[s * 4 + lq][f * 16 + l16][0];
        }
        #pragma unroll
        for (int i = 0; i < 4; ++i)
            #pragma unroll
            for (int j = 0; j < 4; ++j)
                acc[i][j] = __builtin_amdgcn_mfma_f32_16x16x32_bf16(a[i], bb4[j], acc[i][j], 0, 0, 0);
    }

    // ---- epilogue: k-chunked store [kb][n][8] ----
    short* Yb = Ykc + (size_t)b * 32 * N1 * 8;
    #pragma unroll
    for (int i = 0; i < 4; ++i) {
        const int kb = wm * 8 + i * 2 + (lq >> 1);
        const int kr0 = (lq & 1) * 4;
        #pragma unroll
        for (int j = 0; j < 4; ++j) {
            const int n = n0 + j * 16 + l16;
            short4 v = { f2bf(acc[i][j][0]), f2bf(acc[i][j][1]),
                         f2bf(acc[i][j][2]), f2bf(acc[i][j][3]) };
            *(short4*)(Yb + ((size_t)kb * N1 + n) * 8 + kr0) = v;
        }
    }

    // ---- BN partials: each wave owns its 64 channels exclusively -> direct store ----
    #pragma unroll
    for (int i = 0; i < 4; ++i) {
        #pragma unroll
        for (int r = 0; r < 4; ++r) {
            float s = 0.f, qq = 0.f;
            #pragma unroll
            for (int j = 0; j < 4; ++j) {
                float xv = acc[i][j][r];
                s += xv; qq += xv * xv;
            }
            #pragma unroll
            for (int msk = 1; msk < 16; msk <<= 1) {
                s  += __shfl_xor(s, msk);
                qq += __shfl_xor(qq, msk);
            }
            if (l16 == 0) {
                const int c = wm * 64 + i * 16 + lq * 4 + r;
                P[(size_t)c * 1024 + blk] = make_float2(s, qq);
            }
        }
    }
}

// ---------------- BN reduce: partials [256][1024] -> scale/shift ----------------
__global__ __launch_bounds__(256)
void bn_reduce(const float2* __restrict__ P, const float* __restrict__ g,
               const float* __restrict__ be, float* __restrict__ scale,
               float* __restrict__ shift) {
    const int c = blockIdx.x, t = threadIdx.x;
    float s = 0.f, q = 0.f;
    #pragma unroll
    for (int r = 0; r < 4; ++r) {
        float2 v = P[(size_t)c * 1024 + r * 256 + t];
        s += v.x; q += v.y;
    }
    __shared__ float ss[256], sq[256];
    ss[t] = s; sq[t] = q;
    __syncthreads();
    for (int o = 128; o > 0; o >>= 1) {
        if (t < o) { ss[t] += ss[t + o]; sq[t] += sq[t + o]; }
        __syncthreads();
    }
    if (t == 0) {
        const float inv = 1.0f / (float)(BATCH * N1);
        float mean = ss[0] * inv;
        float var  = sq[0] * inv - mean * mean;
        float sc = g[c] / sqrtf(var + BN_EPS);
        scale[c] = sc;
        shift[c] = be[c] - mean * sc;
    }
}

// ---------------- Final BN2+ReLU: y2kc -> f32 out (normal layout) ----------------
__global__ __launch_bounds__(256)
void final_bn_relu(const short* __restrict__ y2kc, const float* __restrict__ scale,
                   const float* __restrict__ shift, float* __restrict__ out) {
    const int t = threadIdx.x;
    const int n0 = blockIdx.x * 1024 + t * 4;
    const int kb = blockIdx.y, b = blockIdx.z;
    const short* src = y2kc + ((size_t)(b * 32 + kb) * N1 + n0) * 8;
    bf16x8 v0 = *(const bf16x8*)(src);
    bf16x8 v1 = *(const bf16x8*)(src + 8);
    bf16x8 v2 = *(const bf16x8*)(src + 16);
    bf16x8 v3 = *(const bf16x8*)(src + 24);
    #pragma unroll
    for (int e = 0; e < 8; ++e) {
        const float sc = scale[kb * 8 + e], sh = shift[kb * 8 + e];
        float4 o;
        o.x = fmaxf(fmaf(bf2f(v0[e]), sc, sh), 0.f);
        o.y = fmaxf(fmaf(bf2f(v1[e]), sc, sh), 0.f);
        o.z = fmaxf(fmaf(bf2f(v2[e]), sc, sh), 0.f);
        o.w = fmaxf(fmaf(bf2f(v3[e]), sc, sh), 0.f);
        *(float4*)(out + ((size_t)(b * 256 + kb * 8 + e) * N1) + n0) = o;
    }
}

extern "C" void kernel_launch(void* const* d_in, const int* in_sizes, int n_in,
                              void* d_out, int out_size, void* d_ws, size_t ws_size,
                              hipStream_t stream) {
    const float* c1  = (const float*)d_in[0];
    const float* c2  = (const float*)d_in[1];
    const float* f1  = (const float*)d_in[2];
    const float* f2  = (const float*)d_in[3];
    const float* W1  = (const float*)d_in[4];
    const float* g1  = (const float*)d_in[6];
    const float* be1 = (const float*)d_in[7];
    const float* W2  = (const float*)d_in[8];
    const float* g2  = (const float*)d_in[10];
    const float* be2 = (const float*)d_in[11];
    float* out = (float*)d_out;

    // ws regions (sequential-kernel overlap, peak ~67.6 MiB):
    // [0,32 MiB):  y1kc (gemm1 -> gemm2)
    // [32,64):     f2t (8 MiB, transpose -> gemm1), then y2kc (gemm2 -> final)
    // [64..):      W1s | W2s | pk | P(2 MiB) | scales
    char* ws = (char*)d_ws;
    short*  y1kc = (short*)ws;
    short*  f2t  = (short*)(ws + (32u << 20));
    short*  y2kc = (short*)(ws + (32u << 20));
    short*  W1s  = (short*)(ws + (64u << 20));
    short*  W2s  = (short*)(ws + (64u << 20) + (256u << 10));
    float4* pk   = (float4*)(ws + (64u << 20) + (512u << 10));
    float2* P    = (float2*)(ws + (64u << 20) + (1536u << 10));
    float* scale1 = (float*)(ws + (64u << 20) + (3584u << 10));
    float* shift1 = scale1 + 256;
    float* scale2 = shift1 + 256;
    float* shift2 = scale2 + 256;

    prep_w<<<48, 256, 0, stream>>>(W1, W1s, CIN);
    prep_w<<<32, 256, 0, stream>>>(W2, W2s, H);
    transpose_f2<<<dim3(N2 / 32, C2 / 32, BATCH), 256, 0, stream>>>(f2, f2t);
    knn_kernel<<<dim3(N1 / 64, BATCH), 512, 0, stream>>>(c1, c2, pk);

    // gemm1: interp fused into one-shot staging (prep_B1 eliminated)
    gemm_kernel<12, false><<<1024, 256, 0, stream>>>(
        W1s, f1, nullptr, f2t, pk, nullptr, nullptr, y1kc, P);
    bn_reduce<<<256, 256, 0, stream>>>(P, g1, be1, scale1, shift1);

    gemm_kernel<8, true><<<1024, 256, 0, stream>>>(
        W2s, nullptr, y1kc, nullptr, nullptr, scale1, shift1, y2kc, P);
    bn_reduce<<<256, 256, 0, stream>>>(P, g2, be2, scale2, shift2);

    final_bn_relu<<<dim3(N1 / 1024, 32, BATCH), 256, 0, stream>>>(y2kc, scale2, shift2, out);
}